// Round 11
// baseline (440.450 us; speedup 1.0000x reference)
//
#include <hip/hip_runtime.h>

typedef _Float16 f16x8 __attribute__((ext_vector_type(8)));
typedef _Float16 f16x4 __attribute__((ext_vector_type(4)));
typedef float f32x4 __attribute__((ext_vector_type(4)));

#define D_IN 768
#define D_H  256
#define SEQ  2048

// async global->LDS, 16B per lane (dest = wave-uniform base + lane*16).
__device__ __forceinline__ void gld16(const void* g, void* l) {
  __builtin_amdgcn_global_load_lds(
      (const __attribute__((address_space(1))) unsigned int*)g,
      (__attribute__((address_space(3))) unsigned int*)l, 16, 0, 0);
}

// ---------------- K0: W1 [768][256] f32 -> W1T [256][768] f16 (transposed) ---
__global__ __launch_bounds__(256) void k0_w1t(const float* __restrict__ W1,
                                              _Float16* __restrict__ W1T) {
  __shared__ float tl[64][65];
  const int kb = blockIdx.x, nb = blockIdx.y, t = threadIdx.x;
#pragma unroll
  for (int rep = 0; rep < 16; ++rep) {
    const int row = rep * 4 + (t >> 6), col = t & 63;
    tl[row][col] = W1[(size_t)(kb * 64 + row) * D_H + nb * 64 + col];
  }
  __syncthreads();
#pragma unroll
  for (int rep = 0; rep < 16; ++rep) {
    const int n = rep * 4 + (t >> 6), k = t & 63;
    W1T[(size_t)(nb * 64 + n) * D_IN + kb * 64 + k] = (_Float16)tl[k][n];
  }
}

// ---------------- KF: fused logits + local softmax + local pooling -----------
// 8192 blocks (16 rows, 48KB CONTIGUOUS A-tile) x 256 thr, 3 blocks/CU.
// kprobe-shaped staging: 12 back-to-back gld16/thread (no dest VGPRs -> cannot
// be regalloc-chunked), sequential addresses. ONE barrier. K-loop barrier-free:
// A from LDS (source-XOR-swizzled chunks), B streamed from L2-resident W1T.
__global__ __launch_bounds__(256, 3) void kf_fused(const float* __restrict__ X,
    const _Float16* __restrict__ W1T, const float* __restrict__ b1,
    const float* __restrict__ C, _Float16* __restrict__ Ppart,
    float* __restrict__ stats) {
  __shared__ float Af[16 * 768];     // 48KB linear; chunk c=(row*192+j) at c*16B
  __shared__ float red2[4][16][4];   // 1KB per-wave logit partials
  __shared__ float red[16][4];       // 256B
  const int t = threadIdx.x;
  const int bid = blockIdx.x;
  const size_t M0 = (size_t)bid * 16;

  const int l = t & 63, w = t >> 6;

  // ---- staging: wave w owns chunks c = w*768 + i*64 + l (4 rows), i=0..11.
  // LDS dest is linear (HW rule); SOURCE chunk is XOR-swizzled: position
  // (row,j) receives X chunk (row, j ^ (row&7)) -> bank-spread b128 reads.
#pragma unroll
  for (int i = 0; i < 12; ++i) {
    const int c = w * 768 + i * 64 + l;
    const int row = c / 192;                 // u24 magic-mul
    const int j = c - row * 192;
    const float* src = X + (M0 + row) * D_IN + ((j ^ (row & 7)) << 2);
    gld16(src, (char*)Af + (size_t)c * 16);
  }
  __syncthreads();   // the ONLY pre-epilogue barrier; 2 other blocks cover it

  // ---- K-loop: 24 x K=32, zero barriers. Wave w owns cols w*64..+64. ----
  const int l15 = l & 15, kg = l >> 4;
  const int s = l15 & 7;                     // row swizzle key (row = l15)
  const _Float16* Bb = W1T + (size_t)(w * 64 + l15) * D_IN + kg * 8;

  f32x4 acc[4];
#pragma unroll
  for (int g = 0; g < 4; ++g) acc[g] = f32x4{0.f, 0.f, 0.f, 0.f};

#pragma unroll
  for (int kt = 0; kt < 24; ++kt) {
    const int j0 = kt * 8 + kg * 2;          // logical 16B-chunk of A-frag
    const f32x4 a0 = *(const f32x4*)&Af[(l15 * 192 + (j0 ^ s)) * 4];
    const f32x4 a1 = *(const f32x4*)&Af[(l15 * 192 + ((j0 + 1) ^ s)) * 4];
    f16x8 af;
    af[0] = (_Float16)a0[0]; af[1] = (_Float16)a0[1];
    af[2] = (_Float16)a0[2]; af[3] = (_Float16)a0[3];
    af[4] = (_Float16)a1[0]; af[5] = (_Float16)a1[1];
    af[6] = (_Float16)a1[2]; af[7] = (_Float16)a1[3];
#pragma unroll
    for (int g = 0; g < 4; ++g) {
      const f16x8 bf = *(const f16x8*)(Bb + (size_t)g * 16 * D_IN + kt * 32);
      acc[g] = __builtin_amdgcn_mfma_f32_16x16x32_f16(af, bf, acc[g], 0, 0, 0);
    }
  }

  // ---- epilogue 1: z -> tanh -> project onto 4 context vectors ----
  float part[4][4];
#pragma unroll
  for (int r = 0; r < 4; ++r)
#pragma unroll
    for (int c = 0; c < 4; ++c) part[r][c] = 0.f;

#pragma unroll
  for (int g = 0; g < 4; ++g) {
    const int col = w * 64 + g * 16 + l15;
    const float4 c4 = *(const float4*)(C + col * 4);
    const float bv = b1[col];
#pragma unroll
    for (int r = 0; r < 4; ++r) {
      float z = acc[g][r] + bv;
      z = fminf(fmaxf(z, -15.f), 15.f);
      const float e = __expf(2.f * z);
      const float h = (e - 1.f) / (e + 1.f);   // tanh(z)
      part[r][0] += h * c4.x;
      part[r][1] += h * c4.y;
      part[r][2] += h * c4.z;
      part[r][3] += h * c4.w;
    }
  }
#pragma unroll
  for (int off = 1; off < 16; off <<= 1) {
#pragma unroll
    for (int r = 0; r < 4; ++r)
#pragma unroll
      for (int c = 0; c < 4; ++c)
        part[r][c] += __shfl_xor(part[r][c], off, 64);
  }
  if (l15 == 0) {   // 4 kg-lanes per wave hold rows kg*4+r
#pragma unroll
    for (int r = 0; r < 4; ++r)
#pragma unroll
      for (int c = 0; c < 4; ++c)
        red2[w][kg * 4 + r][c] = part[r][c];
  }
  __syncthreads();

  // ---- epilogue 2: sum wave partials; block-local softmax (wave 0) ----
  if (t < 64) {
    const int r = t >> 2, c = t & 3;
    red[r][c] = red2[0][r][c] + red2[1][r][c] + red2[2][r][c] + red2[3][r][c];
  }
  __syncthreads();
  if (t < 64) {
    const int c = t >> 4, r = t & 15;        // 4 ctx x 16 rows in wave 0
    const float v = red[r][c];
    float m = v;
#pragma unroll
    for (int off = 1; off < 16; off <<= 1) m = fmaxf(m, __shfl_xor(m, off, 64));
    const float e = __expf(v - m);
    red[r][c] = e;
    float ss = e;
#pragma unroll
    for (int off = 1; off < 16; off <<= 1) ss += __shfl_xor(ss, off, 64);
    if (r == 0) {
      stats[(size_t)bid * 8 + c * 2]     = m;
      stats[(size_t)bid * 8 + c * 2 + 1] = ss;
    }
  }
  __syncthreads();

  // ---- epilogue 3: pooling from LDS (f32): P[c][d] = sum_r e[r][c]*X[r][d] --
  {
    const int c = w;                         // wave c handles context c
#pragma unroll
    for (int seg = 0; seg < 3; ++seg) {
      const int jl = seg * 64 + l;           // logical 16B-chunk 0..191
      float a4[4] = {0.f, 0.f, 0.f, 0.f};
#pragma unroll 4
      for (int r = 0; r < 16; ++r) {
        const float wgt = red[r][c];
        const f32x4 x4 = *(const f32x4*)&Af[(r * 192 + (jl ^ (r & 7))) * 4];
#pragma unroll
        for (int k = 0; k < 4; ++k) a4[k] += wgt * x4[k];
      }
      f16x4 o;
#pragma unroll
      for (int k = 0; k < 4; ++k) o[k] = (_Float16)a4[k];
      *(f16x4*)&Ppart[(size_t)bid * 3072 + c * 768 + jl * 4] = o;
    }
  }
}

// ---------------- KC: combine 128 block-partials per (batch, ctx) -----------
__global__ __launch_bounds__(192) void kc_combine(const _Float16* __restrict__ Ppart,
    const float* __restrict__ stats, float* __restrict__ pooled) {
  const int c = blockIdx.x, b = blockIdx.y, t = threadIdx.x;
  __shared__ float fw[128];
  __shared__ float rpair[2];
  float mv = 0.f, sv = 0.f;
  float m = -3.4e38f;
  if (t < 128) {
    mv = stats[((size_t)(b * 128 + t)) * 8 + c * 2];
    sv = stats[((size_t)(b * 128 + t)) * 8 + c * 2 + 1];
    m = mv;
  }
#pragma unroll
  for (int off = 1; off < 64; off <<= 1) m = fmaxf(m, __shfl_xor(m, off, 64));
  if (t < 128 && (t & 63) == 0) rpair[t >> 6] = m;
  __syncthreads();
  const float M = fmaxf(rpair[0], rpair[1]);
  __syncthreads();
  float f = 0.f;
  if (t < 128) { f = __expf(mv - M); fw[t] = f; }
  float d = f * sv;
#pragma unroll
  for (int off = 1; off < 64; off <<= 1) d += __shfl_xor(d, off, 64);
  if (t < 128 && (t & 63) == 0) rpair[t >> 6] = d;
  __syncthreads();
  const float Dinv = 1.f / (rpair[0] + rpair[1]);

  float a0 = 0.f, a1 = 0.f, a2 = 0.f, a3 = 0.f;
  const _Float16* Pp = Ppart + (size_t)b * 128 * 3072 + c * 768 + t * 4;
#pragma unroll 4
  for (int blk = 0; blk < 128; ++blk) {
    const float wgt = fw[blk];
    const f16x4 v = *(const f16x4*)(Pp + (size_t)blk * 3072);
    a0 += wgt * (float)v[0];
    a1 += wgt * (float)v[1];
    a2 += wgt * (float)v[2];
    a3 += wgt * (float)v[3];
  }
  float4 o;
  o.x = fmaxf(a0 * Dinv, 0.f);
  o.y = fmaxf(a1 * Dinv, 0.f);
  o.z = fmaxf(a2 * Dinv, 0.f);
  o.w = fmaxf(a3 * Dinv, 0.f);
  *(float4*)&pooled[(size_t)b * 3072 + c * 768 + t * 4] = o;
}

// ---------------- K4: partial[kc][b][j] = pooled(k-slice) @ W2(k-slice) ------
__global__ __launch_bounds__(256) void k4_partial(const float* __restrict__ pooled,
                                                  const float* __restrict__ W2,
                                                  float* __restrict__ partial) {
  const int jc = blockIdx.x, kc = blockIdx.y, t = threadIdx.x;
  __shared__ float plds[64 * 192];
  __shared__ float sum2[64][64];
  for (int idx = t; idx < 64 * 192; idx += 256) {
    const int b = idx / 192, k = idx - b * 192;
    plds[idx] = pooled[(size_t)b * 3072 + kc * 192 + k];
  }
  __syncthreads();
  const int j = t & 63, kp = t >> 6;
  float acc[64];
#pragma unroll
  for (int b = 0; b < 64; ++b) acc[b] = 0.f;
  const float* W2p = W2 + (size_t)(kc * 192 + kp * 48) * D_IN + jc * 64 + j;
  const float* pb = plds + kp * 48;
  for (int ki = 0; ki < 48; ki += 4) {
    const float w0 = W2p[(size_t)(ki + 0) * D_IN];
    const float w1 = W2p[(size_t)(ki + 1) * D_IN];
    const float w2 = W2p[(size_t)(ki + 2) * D_IN];
    const float w3 = W2p[(size_t)(ki + 3) * D_IN];
#pragma unroll
    for (int b = 0; b < 64; ++b) {
      const float4 p4 = *(const float4*)(pb + b * 192 + ki);
      acc[b] += p4.x * w0 + p4.y * w1 + p4.z * w2 + p4.w * w3;
    }
  }
#pragma unroll
  for (int p = 0; p < 4; ++p) {
    if (kp == p) {
      if (p == 0) {
#pragma unroll
        for (int b = 0; b < 64; ++b) sum2[b][j] = acc[b];
      } else {
#pragma unroll
        for (int b = 0; b < 64; ++b) sum2[b][j] += acc[b];
      }
    }
    __syncthreads();
  }
  for (int idx = t; idx < 4096; idx += 256) {
    const int b = idx >> 6, jj = idx & 63;
    partial[(size_t)kc * 49152 + (size_t)b * D_IN + jc * 64 + jj] = sum2[b][jj];
  }
}

// ---------------- K5: out = sum(partials) + b2 -------------------------------
__global__ __launch_bounds__(256) void k5_final(const float* __restrict__ partial,
                                                const float* __restrict__ b2,
                                                float* __restrict__ out) {
  const int o = blockIdx.x * 256 + threadIdx.x;
  float v = b2[o % D_IN];
#pragma unroll
  for (int p = 0; p < 16; ++p) v += partial[(size_t)p * 49152 + o];
  out[o] = v;
}

extern "C" void kernel_launch(void* const* d_in, const int* in_sizes, int n_in,
                              void* d_out, int out_size, void* d_ws, size_t ws_size,
                              hipStream_t stream) {
  const float* X  = (const float*)d_in[0];
  const float* W1 = (const float*)d_in[1];
  const float* b1 = (const float*)d_in[2];
  const float* C  = (const float*)d_in[3];
  const float* W2 = (const float*)d_in[4];
  const float* b2 = (const float*)d_in[5];
  float* out = (float*)d_out;
  char* ws = (char*)d_ws;
  _Float16* W1T   = (_Float16*)ws;              //         0 ..   393,216
  float* pooled   = (float*)(ws + 393216);      //   393,216 .. 1,179,648
  float* stats    = (float*)(ws + 1179648);     // 1,179,648 .. 1,441,792
  _Float16* Ppart = (_Float16*)(ws + 1441792);  // 1,441,792 .. 51,773,440
  float* partial  = (float*)(ws + 1441792);     // aliases Ppart (used after KC)

  k0_w1t    <<<dim3(12, 4), 256, 0, stream>>>(W1, W1T);
  kf_fused  <<<8192,        256, 0, stream>>>(X, W1T, b1, C, Ppart, stats);
  kc_combine<<<dim3(4, 64), 192, 0, stream>>>(Ppart, stats, pooled);
  k4_partial<<<dim3(12,16), 256, 0, stream>>>(pooled, W2, partial);
  k5_final  <<<192,         256, 0, stream>>>(partial, b2, out);
}